// Round 1
// baseline (524.808 us; speedup 1.0000x reference)
//
#include <hip/hip_runtime.h>

#define HW (512 * 512)
#define NBINS 256
#define NB 128            // batch
#define P1_ITERS 8        // float4s per thread in pass1
#define P1_BLOCKS (HW / 4 / (256 * P1_ITERS))   // 32 chunks per batch

// ---------------- counts histogram (batch-independent) ----------------
__global__ __launch_bounds__(256) void counts_kernel(const int* __restrict__ bins,
                                                     int* __restrict__ counts) {
    __shared__ int h[NBINS];
    const int tid = threadIdx.x;
    h[tid] = 0;
    __syncthreads();
    const int4* b4 = (const int4*)bins;
    // 64 blocks * 256 threads * 4 int4 = 65536 int4 = HW ints
    for (int it = 0; it < 4; ++it) {
        int idx = blockIdx.x * 1024 + it * 256 + tid;
        int4 v = b4[idx];
        if (v.x > 3 && v.x < NBINS) atomicAdd(&h[v.x], 1);
        if (v.y > 3 && v.y < NBINS) atomicAdd(&h[v.y], 1);
        if (v.z > 3 && v.z < NBINS) atomicAdd(&h[v.z], 1);
        if (v.w > 3 && v.w < NBINS) atomicAdd(&h[v.w], 1);
    }
    __syncthreads();
    if (h[tid]) atomicAdd(&counts[tid], h[tid]);
}

// ---------------- pass 1: per-(batch,bin) S1 = sum|n|, S2 = sum n^2 ----------------
__global__ __launch_bounds__(256) void pass1(const float* __restrict__ parts,
                                             const float* __restrict__ projs,
                                             const int* __restrict__ bins,
                                             float* __restrict__ S1,
                                             float* __restrict__ S2) {
    __shared__ float s1[NBINS];
    __shared__ float s2[NBINS];
    const int tid = threadIdx.x;
    s1[tid] = 0.f;
    s2[tid] = 0.f;
    __syncthreads();

    const int b = blockIdx.y;
    const float4* p4 = (const float4*)parts + (size_t)b * (HW / 4);
    const float4* q4 = (const float4*)projs + (size_t)b * (HW / 4);
    const int4* bn4 = (const int4*)bins;
    const int base = blockIdx.x * (256 * P1_ITERS);

#pragma unroll
    for (int it = 0; it < P1_ITERS; ++it) {
        const int idx = base + it * 256 + tid;
        float4 p = p4[idx];
        float4 q = q4[idx];
        int4 bv = bn4[idx];
        float n0 = p.x - q.x, n1 = p.y - q.y, n2 = p.z - q.z, n3 = p.w - q.w;
        if (bv.x > 3 && bv.x < NBINS) { atomicAdd(&s1[bv.x], fabsf(n0)); atomicAdd(&s2[bv.x], n0 * n0); }
        if (bv.y > 3 && bv.y < NBINS) { atomicAdd(&s1[bv.y], fabsf(n1)); atomicAdd(&s2[bv.y], n1 * n1); }
        if (bv.z > 3 && bv.z < NBINS) { atomicAdd(&s1[bv.z], fabsf(n2)); atomicAdd(&s2[bv.z], n2 * n2); }
        if (bv.w > 3 && bv.w < NBINS) { atomicAdd(&s1[bv.w], fabsf(n3)); atomicAdd(&s2[bv.w], n3 * n3); }
    }
    __syncthreads();
    // one global atomic per (bin) per block; hardware fadd via unsafeAtomicAdd
    unsafeAtomicAdd(&S1[b * NBINS + tid], s1[tid]);
    unsafeAtomicAdd(&S2[b * NBINS + tid], s2[tid]);
}

// ---------------- finalize: per-batch closed-form sum over bins ----------------
__global__ __launch_bounds__(256) void finalize(const float* __restrict__ S1,
                                                const float* __restrict__ S2,
                                                const int* __restrict__ counts,
                                                float* __restrict__ out) {
    const int b = blockIdx.x;
    const int t = threadIdx.x;
    float contrib = 0.f;
    if (t > 3) {  // t < 256 always; valid bins are 4..255
        float c = (float)counts[t];
        float s1 = S1[b * NBINS + t];
        float s2 = S2[b * NBINS + t];
        float mean = s1 / fmaxf(c, 1.f);
        float ssq = fmaxf(s2 - mean * s1, 0.f);          // = sum (a - mean)^2
        float var = ssq / fmaxf(c - 1.f, 1.f);
        // sum over pixels of bin t: -0.5*n^2/var - log(2*pi*var)
        contrib = -0.5f * s2 / var - c * logf(6.283185307179586f * var);
    }
    // block reduction: wave64 shuffle then 4-partial LDS combine
#pragma unroll
    for (int off = 32; off > 0; off >>= 1) contrib += __shfl_down(contrib, off, 64);
    __shared__ float w[4];
    if ((t & 63) == 0) w[t >> 6] = contrib;
    __syncthreads();
    if (t == 0) out[b] = w[0] + w[1] + w[2] + w[3];
}

extern "C" void kernel_launch(void* const* d_in, const int* in_sizes, int n_in,
                              void* d_out, int out_size, void* d_ws, size_t ws_size,
                              hipStream_t stream) {
    const float* parts = (const float*)d_in[0];
    const float* projs = (const float*)d_in[1];
    const int* bins    = (const int*)d_in[2];
    // d_in[3] (valid_mask) and d_in[4] (num_segments) are recomputed/unneeded:
    // valid_mask == (3 < bin < 256), and bins >= 256 never contribute.
    float* out = (float*)d_out;

    int*   counts = (int*)d_ws;                       // 256 ints
    float* S1 = (float*)((char*)d_ws + 1024);         // NB*NBINS floats
    float* S2 = S1 + (size_t)NB * NBINS;              // NB*NBINS floats

    size_t zero_bytes = 1024 + 2 * (size_t)NB * NBINS * sizeof(float);
    hipMemsetAsync(d_ws, 0, zero_bytes, stream);

    counts_kernel<<<64, 256, 0, stream>>>(bins, counts);
    pass1<<<dim3(P1_BLOCKS, NB), 256, 0, stream>>>(parts, projs, bins, S1, S2);
    finalize<<<NB, 256, 0, stream>>>(S1, S2, counts, out);
}